// Round 5
// baseline (2062.609 us; speedup 1.0000x reference)
//
#include <hip/hip_runtime.h>

// ChemicalLLM: x_{t+1} = norm(relu(x + a*einsum(W,x,x))), then big decode GEMM.
//  - recur_kernel: 8 blocks (1/batch), 1024 threads (16 waves). W int8 split:
//    48 j-rows in registers (wreg[48]/lane -> demand ~78, UNDER the ~88-VGPR
//    ceiling the allocator granted in R1-R4) + 16 j-rows in LDS (64 KB,
//    conflict-free ds_read_b128). asm "+v" fences pin wreg (no remat-to-L2,
//    the R1-R4 failure mode). 144 KB LDS forces 1 WG/CU. Wave0 epilogue.
//  - decode_kernel: bf16 MFMA 16x16x32 split-bf16 3-pass (verified layout),
//    LDS-bounced 128B stores, NONTEMPORAL (out is never re-read; skip L2).
//  - prep: W absmax/int8 pack (region A reg-order 48j, region B LDS-order
//    16j); Wd bf16 hi/lo split; emb row-max bound.

typedef unsigned int u32;
typedef unsigned short u16;
typedef __attribute__((ext_vector_type(8))) short short8;
typedef __attribute__((ext_vector_type(4))) float f32x4;
typedef __attribute__((ext_vector_type(4))) int i32x4;

#define DECAY_ 0.1f
#define ALPHA_ 0.2f
#define EPS_ 1e-8f
#define B_ 8
#define S_ 1024
#define N_ 64
#define V_ 32000

// ---------- bf16 helpers (manual, RNE) ----------
static __device__ __forceinline__ u16 f2bf(float f) {
  u32 u = __float_as_uint(f);
  u32 r = (u + 0x7fffu + ((u >> 16) & 1u)) >> 16;
  return (u16)r;
}
static __device__ __forceinline__ float bf2f(u16 h) {
  return __uint_as_float(((u32)h) << 16);
}

// ---------- int8 dot4 ----------
#if defined(__has_builtin)
#if __has_builtin(__builtin_amdgcn_sdot4)
#define HAVE_SDOT4 1
#endif
#endif
static __device__ __forceinline__ int dot4(int a, int b, int c) {
#ifdef HAVE_SDOT4
  return __builtin_amdgcn_sdot4(a, b, c, false);
#else
  int s = c;
  s += (int)(signed char)(a) * (int)(signed char)(b);
  s += (int)(signed char)(a >> 8) * (int)(signed char)(b >> 8);
  s += (int)(signed char)(a >> 16) * (int)(signed char)(b >> 16);
  s += (int)(a >> 24) * (int)(b >> 24);
  return s;
#endif
}

static __device__ __forceinline__ float wave_max64(float v) {
#pragma unroll
  for (int m = 1; m < 64; m <<= 1) v = fmaxf(v, __shfl_xor(v, m, 64));
  return v;
}

// ---------- prep: |W| max ----------
__global__ void wmax_kernel(const float* __restrict__ W, u32* __restrict__ out) {
  int gid = blockIdx.x * blockDim.x + threadIdx.x;
  int stride = gridDim.x * blockDim.x;
  float m = 0.0f;
  for (int i = gid; i < N_ * N_ * N_; i += stride) m = fmaxf(m, fabsf(W[i]));
  m = wave_max64(m);
  if ((threadIdx.x & 63) == 0) atomicMax(out, __float_as_uint(m));  // f>=0: bits monotone
}

// ---------- prep: quantize+pack W into two regions ----------
// canonical dword (j, q, k) packs W[4q+e][j][k], e = byte 0..3.  w=j>>2, r=j&3.
// Region A (r<3, register 48 j's): dst = ((w*3+r)*16 + q)*64 + k
// Region B (r==3, LDS 16 j's):     dst = 49152 + ((w*4 + q>>2)*64 + k)*4 + (q&3)
__global__ void quantw_kernel(const float* __restrict__ W, const u32* __restrict__ wmaxb,
                              u32* __restrict__ Wq) {
  int idx = blockIdx.x * blockDim.x + threadIdx.x;  // 65536 dwords
  float s = 127.0f / fmaxf(__uint_as_float(wmaxb[0]), 1e-30f);
  int j = idx >> 10;
  int q = (idx >> 6) & 15;
  int k = idx & 63;
  u32 pk = 0;
#pragma unroll
  for (int e = 0; e < 4; ++e) {
    float v = W[(((4 * q + e) * N_) + j) * N_ + k];
    int qi = (int)rintf(v * s);
    qi = qi > 127 ? 127 : (qi < -127 ? -127 : qi);
    pk |= ((u32)qi & 0xffu) << (8 * e);
  }
  int w = j >> 2, r = j & 3;
  int dst;
  if (r < 3) {
    dst = ((w * 3 + r) * 16 + q) * 64 + k;
  } else {
    int q4 = q >> 2, e2 = q & 3;
    dst = 49152 + (((w * 4 + q4) * 64 + k) * 4 + e2);
  }
  Wq[dst] = pk;
}

// ---------- prep: Wd -> bf16 hi/lo split ----------
__global__ void wdsplit_kernel(const float* __restrict__ Wd, u16* __restrict__ hi,
                               u16* __restrict__ lo) {
  int idx = blockIdx.x * blockDim.x + threadIdx.x;  // 2048000
  float v = Wd[idx];
  u16 hb = f2bf(v);
  hi[idx] = hb;
  lo[idx] = f2bf(v - bf2f(hb));
}

// ---------- prep: emb row max (bound for x-quant scale) ----------
__global__ void rowmax_kernel(const float* __restrict__ emb, float* __restrict__ rmax) {
  int v = blockIdx.x * 4 + (threadIdx.x >> 6);
  int lane = threadIdx.x & 63;
  float m = wave_max64(emb[(size_t)v * N_ + lane]);
  if (lane == 0) rmax[v] = fmaxf(m, 0.0f);  // max of relu(row)
}

// ---------- the serial recurrence: 1 block per batch, 16 waves ----------
__global__ __launch_bounds__(1024, 4) void recur_kernel(
    const int* __restrict__ ids, const float* __restrict__ emb,
    const u32* __restrict__ Wq, const u32* __restrict__ wmaxb,
    const float* __restrict__ rmax,
    u16* __restrict__ hs_hi, u16* __restrict__ hs_lo, float* __restrict__ outHT) {
  const int b = blockIdx.x;
  const int lane = threadIdx.x & 63;  // k in dot phase
  const int w = threadIdx.x >> 6;     // wave 0..15, owns j in [4w, 4w+4)

  __shared__ i32x4 lw[4096];          // 64 KB: LDS 16 j's, [(w,q4)][lane] 16B units
  __shared__ float pad[20480];        // 80 KB: part/xf/xq + pad to force 1 WG/CU
  float* part = pad;                  // [16][64]
  float* xf_lds = pad + 1024;         // [64] current x (f32, exact)
  u32* xq_lds = (u32*)(pad + 1088);   // [16] x quantized u8, 4/dword along i

  const float sW = __uint_as_float(wmaxb[0]) * (1.0f / 127.0f);

  // Register 48 j's: lane l holds Wq dword for (j=4w+r, r<3, iblock=q, k=l)
  u32 wreg[48];
#pragma unroll
  for (int r = 0; r < 3; ++r) {
#pragma unroll
    for (int q = 0; q < 16; ++q)
      wreg[r * 16 + q] = Wq[((w * 3 + r) * 16 + q) * 64 + lane];
  }
  // opaque fence: defs can't be rematerialized as L2 re-loads (R1-R4 failure)
#pragma unroll
  for (int i = 0; i < 48; ++i) asm volatile("" : "+v"(wreg[i]));

  // LDS 16 j's (j = 4w+3): bulk copy region B (already in lw layout)
  {
    const i32x4* src = (const i32x4*)(Wq + 49152);
    for (int ii = threadIdx.x; ii < 4096; ii += 1024) lw[ii] = src[ii];
  }

  // wave0-private state
  float xk = 0.0f, smul = 0.0f, pend_emb = 0.0f, pend_bnd = 0.0f;
  int pend_id = 0;

  if (w == 0) {
    int id0 = ids[b * S_];
    xk = fmaxf(emb[(size_t)id0 * N_ + lane], 0.0f);  // x_0 (h_0 = 0)
    float bnd = fmaxf(rmax[id0], 1e-20f);            // exact max of x_0
    smul = bnd * (1.0f / 127.0f) * sW;
    float inv = 127.0f / bnd;
    float u = xk * inv;
    float u0 = __shfl(u, (lane & 15) * 4 + 0, 64);
    float u1 = __shfl(u, (lane & 15) * 4 + 1, 64);
    float u2 = __shfl(u, (lane & 15) * 4 + 2, 64);
    float u3 = __shfl(u, (lane & 15) * 4 + 3, 64);
    xf_lds[lane] = xk;
    if (lane < 16) {
      xq_lds[lane] = (u32)(int)rintf(u0) | ((u32)(int)rintf(u1) << 8) |
                     ((u32)(int)rintf(u2) << 16) | ((u32)(int)rintf(u3) << 24);
    }
    int id1 = ids[b * S_ + 1];
    pend_emb = emb[(size_t)id1 * N_ + lane];
    pend_bnd = rmax[id1];
    pend_id = ids[b * S_ + 2];
  }
  __syncthreads();

  for (int t = 0; t < S_; ++t) {
    // ---- dot phase (all 16 waves): raw partial for this wave's 4 j's ----
    u32 pkv = xq_lds[lane & 15];
    int xr[16];
#pragma unroll
    for (int q = 0; q < 16; ++q) xr[q] = __builtin_amdgcn_readlane((int)pkv, q);
    float pf = 0.0f;
    // LDS j (4w+3) first: ds_reads issue early, overlap register-half VALU
    {
      int a = 0;
#pragma unroll
      for (int q4 = 0; q4 < 4; ++q4) {
        i32x4 v = lw[((w << 2) | q4) * 64 + lane];
        a = dot4(xr[4 * q4 + 0], v[0], a);
        a = dot4(xr[4 * q4 + 1], v[1], a);
        a = dot4(xr[4 * q4 + 2], v[2], a);
        a = dot4(xr[4 * q4 + 3], v[3], a);
      }
      pf += (float)a * xf_lds[4 * w + 3];
    }
    // register j's (4w+r, r<3)
#pragma unroll
    for (int r = 0; r < 3; ++r) {
      int a = 0;
#pragma unroll
      for (int q = 0; q < 16; ++q) a = dot4(xr[q], (int)wreg[r * 16 + q], a);
      pf += (float)a * xf_lds[4 * w + r];
    }
    part[(w << 6) | lane] = pf;
    __syncthreads();  // barrier A

    // ---- epilogue (wave0 only) ----
    if (w == 0) {
      float iact = 0.0f;
#pragma unroll
      for (int q = 0; q < 16; ++q) iact += part[(q << 6) | lane];
      float xact = fmaxf(fmaf(ALPHA_ * smul, iact, xk), 0.0f);
      float s = xact;
#pragma unroll
      for (int m = 1; m < 64; m <<= 1) s += __shfl_xor(s, m, 64);
      float rS = 1.0f / (s + EPS_);
      float h = xact * rS;

      int mrow = b * S_ + t;
      u16 hb = f2bf(h);
      hs_hi[(size_t)mrow * N_ + lane] = hb;
      hs_lo[(size_t)mrow * N_ + lane] = f2bf(h - bf2f(hb));
      if (t == S_ - 1) outHT[b * N_ + lane] = h;

      // next state: x_{t+1} = 0.9 h + relu(emb_{t+1});  max(h) <= 1 always
      float wn = fmaxf(pend_emb, 0.0f);
      float xn = fmaf(1.0f - DECAY_, h, wn);
      float nbnd = (1.0f - DECAY_) + pend_bnd;  // >= true max(xn), >= 0.9
      float inv = 127.0f / nbnd;
      float u = xn * inv;
      float u0 = __shfl(u, (lane & 15) * 4 + 0, 64);
      float u1 = __shfl(u, (lane & 15) * 4 + 1, 64);
      float u2 = __shfl(u, (lane & 15) * 4 + 2, 64);
      float u3 = __shfl(u, (lane & 15) * 4 + 3, 64);
      xf_lds[lane] = xn;
      if (lane < 16) {
        xq_lds[lane] = (u32)(int)rintf(u0) | ((u32)(int)rintf(u1) << 8) |
                       ((u32)(int)rintf(u2) << 16) | ((u32)(int)rintf(u3) << 24);
      }
      smul = nbnd * (1.0f / 127.0f) * sW;
      xk = xn;

      // prefetch for t+2
      if (t + 2 < S_) {
        pend_emb = emb[(size_t)pend_id * N_ + lane];
        pend_bnd = rmax[pend_id];
        pend_id = ids[b * S_ + ((t + 3 < S_) ? (t + 3) : (S_ - 1))];
      }
    }
    __syncthreads();  // barrier B
  }
}

// ---------- decode: logits = hs @ Wd^T + bd, split-bf16 3-pass MFMA ----------
__global__ __launch_bounds__(256) void decode_kernel(
    const u16* __restrict__ hs_hi, const u16* __restrict__ hs_lo,
    const u16* __restrict__ wd_hi, const u16* __restrict__ wd_lo,
    const float* __restrict__ bd, float* __restrict__ out) {
  const int lane = threadIdx.x & 63;
  const int w = threadIdx.x >> 6;          // 4 waves, each 16 M-rows
  const int n0 = blockIdx.x * 64;          // V block
  const int mBase = blockIdx.y * 64;
  const int m0 = mBase + w * 16;           // M rows for this wave
  const int row = m0 + (lane & 15);
  const int kg = (lane >> 4) * 8;

  __shared__ float tile[64][68];           // 17.4 KB

  short8 ah0 = *(const short8*)(hs_hi + (size_t)row * N_ + kg);
  short8 ah1 = *(const short8*)(hs_hi + (size_t)row * N_ + 32 + kg);
  short8 al0 = *(const short8*)(hs_lo + (size_t)row * N_ + kg);
  short8 al1 = *(const short8*)(hs_lo + (size_t)row * N_ + 32 + kg);

#pragma unroll
  for (int nt = 0; nt < 4; ++nt) {
    int v = n0 + nt * 16 + (lane & 15);
    short8 bh0 = *(const short8*)(wd_hi + (size_t)v * N_ + kg);
    short8 bh1 = *(const short8*)(wd_hi + (size_t)v * N_ + 32 + kg);
    short8 bl0 = *(const short8*)(wd_lo + (size_t)v * N_ + kg);
    short8 bl1 = *(const short8*)(wd_lo + (size_t)v * N_ + 32 + kg);
    float bdv = bd[v];
    f32x4 acc = {bdv, bdv, bdv, bdv};
    acc = __builtin_amdgcn_mfma_f32_16x16x32_bf16(ah0, bh0, acc, 0, 0, 0);
    acc = __builtin_amdgcn_mfma_f32_16x16x32_bf16(ah1, bh1, acc, 0, 0, 0);
    acc = __builtin_amdgcn_mfma_f32_16x16x32_bf16(ah0, bl0, acc, 0, 0, 0);
    acc = __builtin_amdgcn_mfma_f32_16x16x32_bf16(ah1, bl1, acc, 0, 0, 0);
    acc = __builtin_amdgcn_mfma_f32_16x16x32_bf16(al0, bh0, acc, 0, 0, 0);
    acc = __builtin_amdgcn_mfma_f32_16x16x32_bf16(al1, bh1, acc, 0, 0, 0);
#pragma unroll
    for (int i = 0; i < 4; ++i)
      tile[w * 16 + (lane >> 4) * 4 + i][nt * 16 + (lane & 15)] = acc[i];
  }
  __syncthreads();

  // 128B-contiguous nontemporal stores: out is write-once, never re-read
  int r2 = threadIdx.x >> 3;   // 0..31
  int sg = threadIdx.x & 7;    // 8 threads per row
#pragma unroll
  for (int half = 0; half < 2; ++half) {
    int rrow = half * 32 + r2;
    const float* tr = &tile[rrow][sg * 4];
    f32x4 v0 = *(const f32x4*)(tr);
    f32x4 v1 = *(const f32x4*)(tr + 32);
    float* op = out + (size_t)(mBase + rrow) * V_ + n0 + sg * 4;
    __builtin_nontemporal_store(v0, (f32x4*)op);
    __builtin_nontemporal_store(v1, (f32x4*)(op + 32));
  }
}

// ---------- launch ----------
extern "C" void kernel_launch(void* const* d_in, const int* in_sizes, int n_in,
                              void* d_out, int out_size, void* d_ws, size_t ws_size,
                              hipStream_t stream) {
  const int* ids = (const int*)d_in[0];
  const float* emb = (const float*)d_in[1];
  const float* W = (const float*)d_in[2];
  const float* Wd = (const float*)d_in[3];
  const float* bd = (const float*)d_in[4];
  float* out = (float*)d_out;
  char* ws = (char*)d_ws;

  // ws layout (bytes):
  // [Wq 262144][wmax 64][rowmax 128000][hs_hi 1 MiB][hs_lo 1 MiB][wd_hi 4096000][wd_lo 4096000]
  u32* Wq = (u32*)(ws);
  u32* wmax = (u32*)(ws + 262144);
  float* rmax = (float*)(ws + 262208);
  u16* hs_hi = (u16*)(ws + 390208);
  u16* hs_lo = (u16*)(ws + 1438784);
  u16* wd_hi = (u16*)(ws + 2487360);
  u16* wd_lo = (u16*)(ws + 6583360);

  hipMemsetAsync(wmax, 0, 4, stream);
  hipLaunchKernelGGL(wmax_kernel, dim3(256), dim3(256), 0, stream, W, wmax);
  hipLaunchKernelGGL(quantw_kernel, dim3(256), dim3(256), 0, stream, W, wmax, Wq);
  hipLaunchKernelGGL(rowmax_kernel, dim3(V_ / 4), dim3(256), 0, stream, emb, rmax);
  hipLaunchKernelGGL(wdsplit_kernel, dim3(8000), dim3(256), 0, stream, Wd, wd_hi, wd_lo);
  hipLaunchKernelGGL(recur_kernel, dim3(B_), dim3(1024), 0, stream, ids, emb, Wq, wmax,
                     rmax, hs_hi, hs_lo, out + (size_t)B_ * S_ * V_);
  hipLaunchKernelGGL(decode_kernel, dim3(V_ / 64, (B_ * S_) / 64), dim3(256), 0, stream,
                     hs_hi, hs_lo, wd_hi, wd_lo, bd, out);

  (void)in_sizes; (void)n_in; (void)out_size; (void)ws_size;
}

// Round 6
// 773.275 us; speedup vs baseline: 2.6674x; 2.6674x over previous
//
#include <hip/hip_runtime.h>

// ChemicalLLM: x_{t+1} = norm(relu(x + a*einsum(W,x,x))), then big decode GEMM.
//  KEY IDEA (R6): the recurrence contracts at ~0.05/step (h is L1-normalized
//  to 1 vs word mass ~26, so renormalization divides perturbations by S~26).
//  => chunk the 1024 steps into 16 chunks of 64 with 48 warmup steps from
//  h=0 (exactly the t=0 init formula). 128 independent blocks, sequential
//  depth 112 instead of 1024. Warmup IC error <= gamma^48 ~ 1e-60 (even
//  gamma=0.5 gives 3.5e-15) -- invisible vs the 4.9e-4 bf16 floor.
//  - per-block step structure = R4 verbatim (measured 1.34 us/step): W int8,
//    32 j's in LDS (128 KB, conflict-free ds_read_b128) + 32 j's via L1/L2
//    reload (register residency is unobtainable: R1-R5, allocator caps ~88).
//  - decode_kernel: bf16 MFMA 16x16x32 split-bf16 3-pass, LDS-bounced 128B
//    nontemporal stores. Untouched this round (counters finally visible).

typedef unsigned int u32;
typedef unsigned short u16;
typedef __attribute__((ext_vector_type(8))) short short8;
typedef __attribute__((ext_vector_type(4))) float f32x4;
typedef __attribute__((ext_vector_type(4))) int i32x4;

#define DECAY_ 0.1f
#define ALPHA_ 0.2f
#define EPS_ 1e-8f
#define B_ 8
#define S_ 1024
#define N_ 64
#define V_ 32000
#define NCHUNK_ 16
#define CHUNK_ 64
#define WARM_ 48

// ---------- bf16 helpers (manual, RNE) ----------
static __device__ __forceinline__ u16 f2bf(float f) {
  u32 u = __float_as_uint(f);
  u32 r = (u + 0x7fffu + ((u >> 16) & 1u)) >> 16;
  return (u16)r;
}
static __device__ __forceinline__ float bf2f(u16 h) {
  return __uint_as_float(((u32)h) << 16);
}

// ---------- int8 dot4 ----------
#if defined(__has_builtin)
#if __has_builtin(__builtin_amdgcn_sdot4)
#define HAVE_SDOT4 1
#endif
#endif
static __device__ __forceinline__ int dot4(int a, int b, int c) {
#ifdef HAVE_SDOT4
  return __builtin_amdgcn_sdot4(a, b, c, false);
#else
  int s = c;
  s += (int)(signed char)(a) * (int)(signed char)(b);
  s += (int)(signed char)(a >> 8) * (int)(signed char)(b >> 8);
  s += (int)(signed char)(a >> 16) * (int)(signed char)(b >> 16);
  s += (int)(a >> 24) * (int)(b >> 24);
  return s;
#endif
}

static __device__ __forceinline__ float wave_max64(float v) {
#pragma unroll
  for (int m = 1; m < 64; m <<= 1) v = fmaxf(v, __shfl_xor(v, m, 64));
  return v;
}

// ---------- prep: |W| max ----------
__global__ void wmax_kernel(const float* __restrict__ W, u32* __restrict__ out) {
  int gid = blockIdx.x * blockDim.x + threadIdx.x;
  int stride = gridDim.x * blockDim.x;
  float m = 0.0f;
  for (int i = gid; i < N_ * N_ * N_; i += stride) m = fmaxf(m, fabsf(W[i]));
  m = wave_max64(m);
  if ((threadIdx.x & 63) == 0) atomicMax(out, __float_as_uint(m));  // f>=0: bits monotone
}

// ---------- prep: quantize+pack W into two regions ----------
// canonical dword (j, q, k) packs W[4q+e][j][k], e = byte 0..3.  w=j>>3, r=j&7.
// Region A (r<4, "L2 half"):   dst = ((w*4+r)*16 + q)*64 + k
// Region B (r>=4, "LDS half"): dst = 32768 + ((( (w*4+(r-4))*4 + q>>2)*64 + k)*4 + (q&3))
__global__ void quantw_kernel(const float* __restrict__ W, const u32* __restrict__ wmaxb,
                              u32* __restrict__ Wq) {
  int idx = blockIdx.x * blockDim.x + threadIdx.x;  // 65536 dwords
  float s = 127.0f / fmaxf(__uint_as_float(wmaxb[0]), 1e-30f);
  int j = idx >> 10;
  int q = (idx >> 6) & 15;
  int k = idx & 63;
  u32 pk = 0;
#pragma unroll
  for (int e = 0; e < 4; ++e) {
    float v = W[(((4 * q + e) * N_) + j) * N_ + k];
    int qi = (int)rintf(v * s);
    qi = qi > 127 ? 127 : (qi < -127 ? -127 : qi);
    pk |= ((u32)qi & 0xffu) << (8 * e);
  }
  int w = j >> 3, r = j & 7;
  int dst;
  if (r < 4) {
    dst = ((w * 4 + r) * 16 + q) * 64 + k;
  } else {
    int jL = w * 4 + (r - 4);
    int q4 = q >> 2, e2 = q & 3;
    dst = 32768 + (((jL * 4 + q4) * 64 + k) * 4 + e2);
  }
  Wq[dst] = pk;
}

// ---------- prep: Wd -> bf16 hi/lo split ----------
__global__ void wdsplit_kernel(const float* __restrict__ Wd, u16* __restrict__ hi,
                               u16* __restrict__ lo) {
  int idx = blockIdx.x * blockDim.x + threadIdx.x;  // 2048000
  float v = Wd[idx];
  u16 hb = f2bf(v);
  hi[idx] = hb;
  lo[idx] = f2bf(v - bf2f(hb));
}

// ---------- prep: emb row max (bound for x-quant scale) ----------
__global__ void rowmax_kernel(const float* __restrict__ emb, float* __restrict__ rmax) {
  int v = blockIdx.x * 4 + (threadIdx.x >> 6);
  int lane = threadIdx.x & 63;
  float m = wave_max64(emb[(size_t)v * N_ + lane]);
  if (lane == 0) rmax[v] = fmaxf(m, 0.0f);  // max of relu(row)
}

// ---------- recurrence: blockIdx.y = batch, blockIdx.x = chunk ----------
__global__ __launch_bounds__(512, 2) void recur_kernel(
    const int* __restrict__ ids, const float* __restrict__ emb,
    const u32* __restrict__ Wq, const u32* __restrict__ wmaxb,
    const float* __restrict__ rmax,
    u16* __restrict__ hs_hi, u16* __restrict__ hs_lo, float* __restrict__ outHT) {
  const int b = blockIdx.y;
  const int chunk = blockIdx.x;
  const int lane = threadIdx.x & 63;  // k in dot phase
  const int w = threadIdx.x >> 6;     // wave 0..7, owns j in [8w, 8w+8)

  const int t0 = chunk * CHUNK_;                 // first step this chunk OWNS
  const int ts = (chunk == 0) ? 0 : t0 - WARM_;  // warmup start (h=0 IC: exact at t=0)
  const int tend = t0 + CHUNK_;

  __shared__ i32x4 lw[8192];      // 128 KB: LDS half of W, [jL][q4][lane] 16B units
  __shared__ float part[8 * 64];  // raw partials (unscaled)
  __shared__ float xf_lds[N_];    // current x (f32, exact)
  __shared__ u32 xq_lds[16];      // current x quantized u8, 4/dword along i

  const float sW = __uint_as_float(wmaxb[0]) * (1.0f / 127.0f);

  // "L2 half": lane l nominally holds Wq dword for (j=8w+r, r<4, iblock=q, k=l).
  // (Allocator will reload these from L1/L2 per step - R1-R5 showed residency
  //  is unobtainable; at 1 block/CU this is ~0.55 us/step, acceptable.)
  u32 wreg[64];
#pragma unroll
  for (int r = 0; r < 4; ++r) {
#pragma unroll
    for (int q = 0; q < 16; ++q)
      wreg[r * 16 + q] = Wq[(((w << 2) + r) << 10) + (q << 6) + lane];
  }
  // LDS half: bulk copy region B (already in lw layout)
  {
    const i32x4* src = (const i32x4*)(Wq + 32768);
    for (int ii = threadIdx.x; ii < 8192; ii += 512) lw[ii] = src[ii];
  }

  // wave0-private state
  float xk = 0.0f, smul = 0.0f, pend_emb = 0.0f, pend_bnd = 0.0f;
  int pend_id = 0;

  if (w == 0) {
    int id0 = ids[b * S_ + ts];
    xk = fmaxf(emb[(size_t)id0 * N_ + lane], 0.0f);  // x_ts with h=0 IC
    float bnd = fmaxf(rmax[id0], 1e-20f);            // exact max of x_ts
    smul = bnd * (1.0f / 127.0f) * sW;
    float inv = 127.0f / bnd;
    float u = xk * inv;
    float u0 = __shfl(u, (lane & 15) * 4 + 0, 64);
    float u1 = __shfl(u, (lane & 15) * 4 + 1, 64);
    float u2 = __shfl(u, (lane & 15) * 4 + 2, 64);
    float u3 = __shfl(u, (lane & 15) * 4 + 3, 64);
    xf_lds[lane] = xk;
    if (lane < 16) {
      xq_lds[lane] = (u32)(int)rintf(u0) | ((u32)(int)rintf(u1) << 8) |
                     ((u32)(int)rintf(u2) << 16) | ((u32)(int)rintf(u3) << 24);
    }
    int i1 = ts + 1 < S_ ? ts + 1 : S_ - 1;
    int i2 = ts + 2 < S_ ? ts + 2 : S_ - 1;
    int id1 = ids[b * S_ + i1];
    pend_emb = emb[(size_t)id1 * N_ + lane];
    pend_bnd = rmax[id1];
    pend_id = ids[b * S_ + i2];
  }
  __syncthreads();

  for (int t = ts; t < tend; ++t) {
    // ---- dot phase (all 8 waves): raw partial for this wave's 8 j's ----
    u32 pkv = xq_lds[lane & 15];
    int xr[16];
#pragma unroll
    for (int q = 0; q < 16; ++q) xr[q] = __builtin_amdgcn_readlane((int)pkv, q);
    float pf = 0.0f;
    // LDS half first (j = 8w+4+r4): ds_reads issue early, overlap L2-half VALU
#pragma unroll
    for (int r4 = 0; r4 < 4; ++r4) {
      int a = 0;
#pragma unroll
      for (int q4 = 0; q4 < 4; ++q4) {
        i32x4 v = lw[(((w << 2) + r4) << 2 | q4) * 64 + lane];
        a = dot4(xr[4 * q4 + 0], v[0], a);
        a = dot4(xr[4 * q4 + 1], v[1], a);
        a = dot4(xr[4 * q4 + 2], v[2], a);
        a = dot4(xr[4 * q4 + 3], v[3], a);
      }
      pf += (float)a * xf_lds[8 * w + 4 + r4];
    }
    // L2 half (j = 8w+r, r<4)
#pragma unroll
    for (int r = 0; r < 4; ++r) {
      int a = 0;
#pragma unroll
      for (int q = 0; q < 16; ++q) a = dot4(xr[q], (int)wreg[r * 16 + q], a);
      pf += (float)a * xf_lds[8 * w + r];
    }
    part[(w << 6) | lane] = pf;
    __syncthreads();  // barrier A

    // ---- epilogue (wave0 only) ----
    if (w == 0) {
      float iact = 0.0f;
#pragma unroll
      for (int q = 0; q < 8; ++q) iact += part[(q << 6) | lane];
      float xact = fmaxf(fmaf(ALPHA_ * smul, iact, xk), 0.0f);
      float s = xact;
#pragma unroll
      for (int m = 1; m < 64; m <<= 1) s += __shfl_xor(s, m, 64);
      float rS = 1.0f / (s + EPS_);
      float h = xact * rS;

      if (t >= t0) {  // chunk owns this step
        int mrow = b * S_ + t;
        u16 hb = f2bf(h);
        hs_hi[(size_t)mrow * N_ + lane] = hb;
        hs_lo[(size_t)mrow * N_ + lane] = f2bf(h - bf2f(hb));
        if (t == S_ - 1) outHT[b * N_ + lane] = h;
      }

      // next state: x_{t+1} = 0.9 h + relu(emb_{t+1});  max(h) <= 1 always
      float wn = fmaxf(pend_emb, 0.0f);
      float xn = fmaf(1.0f - DECAY_, h, wn);
      float nbnd = (1.0f - DECAY_) + pend_bnd;  // >= true max(xn), >= 0.9
      float inv = 127.0f / nbnd;
      float u = xn * inv;
      float u0 = __shfl(u, (lane & 15) * 4 + 0, 64);
      float u1 = __shfl(u, (lane & 15) * 4 + 1, 64);
      float u2 = __shfl(u, (lane & 15) * 4 + 2, 64);
      float u3 = __shfl(u, (lane & 15) * 4 + 3, 64);
      xf_lds[lane] = xn;
      if (lane < 16) {
        xq_lds[lane] = (u32)(int)rintf(u0) | ((u32)(int)rintf(u1) << 8) |
                       ((u32)(int)rintf(u2) << 16) | ((u32)(int)rintf(u3) << 24);
      }
      smul = nbnd * (1.0f / 127.0f) * sW;
      xk = xn;

      // prefetch for t+2 (clamped; values past tend are unused)
      int i2 = t + 3 < S_ ? t + 3 : S_ - 1;
      pend_emb = emb[(size_t)pend_id * N_ + lane];
      pend_bnd = rmax[pend_id];
      pend_id = ids[b * S_ + i2];
    }
    __syncthreads();  // barrier B
  }
}

// ---------- decode: logits = hs @ Wd^T + bd, split-bf16 3-pass MFMA ----------
__global__ __launch_bounds__(256) void decode_kernel(
    const u16* __restrict__ hs_hi, const u16* __restrict__ hs_lo,
    const u16* __restrict__ wd_hi, const u16* __restrict__ wd_lo,
    const float* __restrict__ bd, float* __restrict__ out) {
  const int lane = threadIdx.x & 63;
  const int w = threadIdx.x >> 6;          // 4 waves, each 16 M-rows
  const int n0 = blockIdx.x * 64;          // V block
  const int mBase = blockIdx.y * 64;
  const int m0 = mBase + w * 16;           // M rows for this wave
  const int row = m0 + (lane & 15);
  const int kg = (lane >> 4) * 8;

  __shared__ float tile[64][68];           // 17.4 KB

  short8 ah0 = *(const short8*)(hs_hi + (size_t)row * N_ + kg);
  short8 ah1 = *(const short8*)(hs_hi + (size_t)row * N_ + 32 + kg);
  short8 al0 = *(const short8*)(hs_lo + (size_t)row * N_ + kg);
  short8 al1 = *(const short8*)(hs_lo + (size_t)row * N_ + 32 + kg);

#pragma unroll
  for (int nt = 0; nt < 4; ++nt) {
    int v = n0 + nt * 16 + (lane & 15);
    short8 bh0 = *(const short8*)(wd_hi + (size_t)v * N_ + kg);
    short8 bh1 = *(const short8*)(wd_hi + (size_t)v * N_ + 32 + kg);
    short8 bl0 = *(const short8*)(wd_lo + (size_t)v * N_ + kg);
    short8 bl1 = *(const short8*)(wd_lo + (size_t)v * N_ + 32 + kg);
    float bdv = bd[v];
    f32x4 acc = {bdv, bdv, bdv, bdv};
    acc = __builtin_amdgcn_mfma_f32_16x16x32_bf16(ah0, bh0, acc, 0, 0, 0);
    acc = __builtin_amdgcn_mfma_f32_16x16x32_bf16(ah1, bh1, acc, 0, 0, 0);
    acc = __builtin_amdgcn_mfma_f32_16x16x32_bf16(ah0, bl0, acc, 0, 0, 0);
    acc = __builtin_amdgcn_mfma_f32_16x16x32_bf16(ah1, bl1, acc, 0, 0, 0);
    acc = __builtin_amdgcn_mfma_f32_16x16x32_bf16(al0, bh0, acc, 0, 0, 0);
    acc = __builtin_amdgcn_mfma_f32_16x16x32_bf16(al1, bh1, acc, 0, 0, 0);
#pragma unroll
    for (int i = 0; i < 4; ++i)
      tile[w * 16 + (lane >> 4) * 4 + i][nt * 16 + (lane & 15)] = acc[i];
  }
  __syncthreads();

  // 128B-contiguous nontemporal stores: out is write-once, never re-read
  int r2 = threadIdx.x >> 3;   // 0..31
  int sg = threadIdx.x & 7;    // 8 threads per row
#pragma unroll
  for (int half = 0; half < 2; ++half) {
    int rrow = half * 32 + r2;
    const float* tr = &tile[rrow][sg * 4];
    f32x4 v0 = *(const f32x4*)(tr);
    f32x4 v1 = *(const f32x4*)(tr + 32);
    float* op = out + (size_t)(mBase + rrow) * V_ + n0 + sg * 4;
    __builtin_nontemporal_store(v0, (f32x4*)op);
    __builtin_nontemporal_store(v1, (f32x4*)(op + 32));
  }
}

// ---------- launch ----------
extern "C" void kernel_launch(void* const* d_in, const int* in_sizes, int n_in,
                              void* d_out, int out_size, void* d_ws, size_t ws_size,
                              hipStream_t stream) {
  const int* ids = (const int*)d_in[0];
  const float* emb = (const float*)d_in[1];
  const float* W = (const float*)d_in[2];
  const float* Wd = (const float*)d_in[3];
  const float* bd = (const float*)d_in[4];
  float* out = (float*)d_out;
  char* ws = (char*)d_ws;

  // ws layout (bytes):
  // [Wq 262144][wmax 64][rowmax 128000][hs_hi 1 MiB][hs_lo 1 MiB][wd_hi 4096000][wd_lo 4096000]
  u32* Wq = (u32*)(ws);
  u32* wmax = (u32*)(ws + 262144);
  float* rmax = (float*)(ws + 262208);
  u16* hs_hi = (u16*)(ws + 390208);
  u16* hs_lo = (u16*)(ws + 1438784);
  u16* wd_hi = (u16*)(ws + 2487360);
  u16* wd_lo = (u16*)(ws + 6583360);

  hipMemsetAsync(wmax, 0, 4, stream);
  hipLaunchKernelGGL(wmax_kernel, dim3(256), dim3(256), 0, stream, W, wmax);
  hipLaunchKernelGGL(quantw_kernel, dim3(256), dim3(256), 0, stream, W, wmax, Wq);
  hipLaunchKernelGGL(rowmax_kernel, dim3(V_ / 4), dim3(256), 0, stream, emb, rmax);
  hipLaunchKernelGGL(wdsplit_kernel, dim3(8000), dim3(256), 0, stream, Wd, wd_hi, wd_lo);
  hipLaunchKernelGGL(recur_kernel, dim3(NCHUNK_, B_), dim3(512), 0, stream, ids, emb,
                     Wq, wmax, rmax, hs_hi, hs_lo, out + (size_t)B_ * S_ * V_);
  hipLaunchKernelGGL(decode_kernel, dim3(V_ / 64, (B_ * S_) / 64), dim3(256), 0, stream,
                     hs_hi, hs_lo, wd_hi, wd_lo, bd, out);

  (void)in_sizes; (void)n_in; (void)out_size; (void)ws_size;
}

// Round 7
// 392.868 us; speedup vs baseline: 5.2501x; 1.9683x over previous
//
#include <hip/hip_runtime.h>

// ChemicalLLM: x_{t+1} = norm(relu(x + a*einsum(W,x,x))), then big decode GEMM.
//  R6 result: chunked-parallel scan works (contraction gamma<=0.15), absmax
//  unchanged. R7 changes:
//  - decode: SINGLE-PASS bf16 (L1 bound: h>=0, sum(h)=1 => err <= 2^-9*max|Wd|
//    per rounding source ~ 3.6e-4 total, threshold 2.4e-3), 128x128 tiles,
//    wd_bf16 = 4 MB fits per-XCD L2. Write-bound now (~1.05 GB out).
//  - recur: WARM 48->32 (depth 96; gamma^32 invisible), region A repacked to
//    the same [j][q4][k][e2] layout as region B -> L2-half streams as
//    dwordx4 (4x fewer VMEM issues per step).
//  - per-CU step cost model (validated on R4): DS 0.64 + L2 0.47 + VALU 0.28,
//    pipes nearly additive at 2 waves/SIMD.

typedef unsigned int u32;
typedef unsigned short u16;
typedef __attribute__((ext_vector_type(8))) short short8;
typedef __attribute__((ext_vector_type(4))) float f32x4;
typedef __attribute__((ext_vector_type(4))) int i32x4;

#define DECAY_ 0.1f
#define ALPHA_ 0.2f
#define EPS_ 1e-8f
#define B_ 8
#define S_ 1024
#define N_ 64
#define V_ 32000
#define NCHUNK_ 16
#define CHUNK_ 64
#define WARM_ 32

// ---------- bf16 helpers (manual, RNE) ----------
static __device__ __forceinline__ u16 f2bf(float f) {
  u32 u = __float_as_uint(f);
  u32 r = (u + 0x7fffu + ((u >> 16) & 1u)) >> 16;
  return (u16)r;
}

// ---------- int8 dot4 ----------
#if defined(__has_builtin)
#if __has_builtin(__builtin_amdgcn_sdot4)
#define HAVE_SDOT4 1
#endif
#endif
static __device__ __forceinline__ int dot4(int a, int b, int c) {
#ifdef HAVE_SDOT4
  return __builtin_amdgcn_sdot4(a, b, c, false);
#else
  int s = c;
  s += (int)(signed char)(a) * (int)(signed char)(b);
  s += (int)(signed char)(a >> 8) * (int)(signed char)(b >> 8);
  s += (int)(signed char)(a >> 16) * (int)(signed char)(b >> 16);
  s += (int)(a >> 24) * (int)(b >> 24);
  return s;
#endif
}

static __device__ __forceinline__ float wave_max64(float v) {
#pragma unroll
  for (int m = 1; m < 64; m <<= 1) v = fmaxf(v, __shfl_xor(v, m, 64));
  return v;
}

// ---------- prep: |W| max ----------
__global__ void wmax_kernel(const float* __restrict__ W, u32* __restrict__ out) {
  int gid = blockIdx.x * blockDim.x + threadIdx.x;
  int stride = gridDim.x * blockDim.x;
  float m = 0.0f;
  for (int i = gid; i < N_ * N_ * N_; i += stride) m = fmaxf(m, fabsf(W[i]));
  m = wave_max64(m);
  if ((threadIdx.x & 63) == 0) atomicMax(out, __float_as_uint(m));  // f>=0: bits monotone
}

// ---------- prep: quantize+pack W ----------
// canonical dword (j, q, k) packs W[4q+e][j][k], e = byte 0..3.  w=j>>3, r=j&7.
// BOTH halves use layout dst = base + ((jX*4 + q4)*64 + k)*4 + e2,
// jX = w*4 + (r&3); base = 0 (r<4, "L2 half") or 32768 (r>=4, "LDS half").
__global__ void quantw_kernel(const float* __restrict__ W, const u32* __restrict__ wmaxb,
                              u32* __restrict__ Wq) {
  int idx = blockIdx.x * blockDim.x + threadIdx.x;  // 65536 dwords
  float s = 127.0f / fmaxf(__uint_as_float(wmaxb[0]), 1e-30f);
  int j = idx >> 10;
  int q = (idx >> 6) & 15;
  int k = idx & 63;
  u32 pk = 0;
#pragma unroll
  for (int e = 0; e < 4; ++e) {
    float v = W[(((4 * q + e) * N_) + j) * N_ + k];
    int qi = (int)rintf(v * s);
    qi = qi > 127 ? 127 : (qi < -127 ? -127 : qi);
    pk |= ((u32)qi & 0xffu) << (8 * e);
  }
  int w = j >> 3, r = j & 7;
  int jX = w * 4 + (r & 3);
  int base = (r < 4) ? 0 : 32768;
  int q4 = q >> 2, e2 = q & 3;
  Wq[base + (((jX * 4 + q4) * 64 + k) << 2) + e2] = pk;
}

// ---------- prep: Wd -> bf16 ----------
__global__ void wdbf16_kernel(const float* __restrict__ Wd, u16* __restrict__ hi) {
  int idx = blockIdx.x * blockDim.x + threadIdx.x;  // 2048000
  hi[idx] = f2bf(Wd[idx]);
}

// ---------- prep: emb row max (bound for x-quant scale) ----------
__global__ void rowmax_kernel(const float* __restrict__ emb, float* __restrict__ rmax) {
  int v = blockIdx.x * 4 + (threadIdx.x >> 6);
  int lane = threadIdx.x & 63;
  float m = wave_max64(emb[(size_t)v * N_ + lane]);
  if (lane == 0) rmax[v] = fmaxf(m, 0.0f);  // max of relu(row)
}

// ---------- recurrence: blockIdx.y = batch, blockIdx.x = chunk ----------
__global__ __launch_bounds__(512, 2) void recur_kernel(
    const int* __restrict__ ids, const float* __restrict__ emb,
    const u32* __restrict__ Wq, const u32* __restrict__ wmaxb,
    const float* __restrict__ rmax,
    u16* __restrict__ hs, float* __restrict__ outHT) {
  const int b = blockIdx.y;
  const int chunk = blockIdx.x;
  const int lane = threadIdx.x & 63;  // k in dot phase
  const int w = threadIdx.x >> 6;     // wave 0..7, owns j in [8w, 8w+8)

  const int t0 = chunk * CHUNK_;                 // first step this chunk OWNS
  const int ts = (chunk == 0) ? 0 : t0 - WARM_;  // warmup start (h=0 IC exact at t=0)
  const int tend = t0 + CHUNK_;

  __shared__ i32x4 lw[8192];      // 128 KB: LDS half of W, [jB][q4][lane] 16B units
  __shared__ float part[8 * 64];  // raw partials (unscaled)
  __shared__ float xf_lds[N_];    // current x (f32, exact)
  __shared__ u32 xq_lds[16];      // current x quantized u8, 4/dword along i

  const float sW = __uint_as_float(wmaxb[0]) * (1.0f / 127.0f);
  const i32x4* __restrict__ WqA = (const i32x4*)Wq;  // L2 half, x4 layout

  // LDS half: bulk copy region B (already in lw layout)
  {
    const i32x4* src = (const i32x4*)(Wq + 32768);
    for (int ii = threadIdx.x; ii < 8192; ii += 512) lw[ii] = src[ii];
  }

  // wave0-private state
  float xk = 0.0f, smul = 0.0f, pend_emb = 0.0f, pend_bnd = 0.0f;
  int pend_id = 0;

  if (w == 0) {
    int id0 = ids[b * S_ + ts];
    xk = fmaxf(emb[(size_t)id0 * N_ + lane], 0.0f);  // x_ts with h=0 IC
    float bnd = fmaxf(rmax[id0], 1e-20f);            // exact max of x_ts
    smul = bnd * (1.0f / 127.0f) * sW;
    float inv = 127.0f / bnd;
    float u = xk * inv;
    float u0 = __shfl(u, (lane & 15) * 4 + 0, 64);
    float u1 = __shfl(u, (lane & 15) * 4 + 1, 64);
    float u2 = __shfl(u, (lane & 15) * 4 + 2, 64);
    float u3 = __shfl(u, (lane & 15) * 4 + 3, 64);
    xf_lds[lane] = xk;
    if (lane < 16) {
      xq_lds[lane] = (u32)(int)rintf(u0) | ((u32)(int)rintf(u1) << 8) |
                     ((u32)(int)rintf(u2) << 16) | ((u32)(int)rintf(u3) << 24);
    }
    int i1 = ts + 1 < S_ ? ts + 1 : S_ - 1;
    int i2 = ts + 2 < S_ ? ts + 2 : S_ - 1;
    int id1 = ids[b * S_ + i1];
    pend_emb = emb[(size_t)id1 * N_ + lane];
    pend_bnd = rmax[id1];
    pend_id = ids[b * S_ + i2];
  }
  __syncthreads();

  for (int t = ts; t < tend; ++t) {
    // ---- dot phase (all 8 waves): raw partial for this wave's 8 j's ----
    u32 pkv = xq_lds[lane & 15];
    int xr[16];
#pragma unroll
    for (int q = 0; q < 16; ++q) xr[q] = __builtin_amdgcn_readlane((int)pkv, q);
    float pf = 0.0f;
    // LDS half (j = 8w+4+r4)
#pragma unroll
    for (int r4 = 0; r4 < 4; ++r4) {
      int a = 0;
#pragma unroll
      for (int q4 = 0; q4 < 4; ++q4) {
        i32x4 v = lw[(((w << 2) + r4) << 2 | q4) * 64 + lane];
        a = dot4(xr[4 * q4 + 0], v[0], a);
        a = dot4(xr[4 * q4 + 1], v[1], a);
        a = dot4(xr[4 * q4 + 2], v[2], a);
        a = dot4(xr[4 * q4 + 3], v[3], a);
      }
      pf += (float)a * xf_lds[8 * w + 4 + r4];
    }
    // L2 half (j = 8w+r, r<4): streamed dwordx4 each step
#pragma unroll
    for (int r = 0; r < 4; ++r) {
      int a = 0;
#pragma unroll
      for (int q4 = 0; q4 < 4; ++q4) {
        i32x4 v = WqA[(((w << 2) + r) << 2 | q4) * 64 + lane];
        a = dot4(xr[4 * q4 + 0], v[0], a);
        a = dot4(xr[4 * q4 + 1], v[1], a);
        a = dot4(xr[4 * q4 + 2], v[2], a);
        a = dot4(xr[4 * q4 + 3], v[3], a);
      }
      pf += (float)a * xf_lds[8 * w + r];
    }
    part[(w << 6) | lane] = pf;
    __syncthreads();  // barrier A

    // ---- epilogue (wave0 only) ----
    if (w == 0) {
      float iact = 0.0f;
#pragma unroll
      for (int q = 0; q < 8; ++q) iact += part[(q << 6) | lane];
      float xact = fmaxf(fmaf(ALPHA_ * smul, iact, xk), 0.0f);
      float s = xact;
#pragma unroll
      for (int m = 1; m < 64; m <<= 1) s += __shfl_xor(s, m, 64);
      float rS = 1.0f / (s + EPS_);
      float h = xact * rS;

      if (t >= t0) {  // chunk owns this step
        int mrow = b * S_ + t;
        hs[(size_t)mrow * N_ + lane] = f2bf(h);
        if (t == S_ - 1) outHT[b * N_ + lane] = h;
      }

      // next state: x_{t+1} = 0.9 h + relu(emb_{t+1});  max(h) <= 1 always
      float wn = fmaxf(pend_emb, 0.0f);
      float xn = fmaf(1.0f - DECAY_, h, wn);
      float nbnd = (1.0f - DECAY_) + pend_bnd;  // >= true max(xn), >= 0.9
      float inv = 127.0f / nbnd;
      float u = xn * inv;
      float u0 = __shfl(u, (lane & 15) * 4 + 0, 64);
      float u1 = __shfl(u, (lane & 15) * 4 + 1, 64);
      float u2 = __shfl(u, (lane & 15) * 4 + 2, 64);
      float u3 = __shfl(u, (lane & 15) * 4 + 3, 64);
      xf_lds[lane] = xn;
      if (lane < 16) {
        xq_lds[lane] = (u32)(int)rintf(u0) | ((u32)(int)rintf(u1) << 8) |
                       ((u32)(int)rintf(u2) << 16) | ((u32)(int)rintf(u3) << 24);
      }
      smul = nbnd * (1.0f / 127.0f) * sW;
      xk = xn;

      // prefetch for t+2 (clamped; values past tend are unused)
      int i2 = t + 3 < S_ ? t + 3 : S_ - 1;
      pend_emb = emb[(size_t)pend_id * N_ + lane];
      pend_bnd = rmax[pend_id];
      pend_id = ids[b * S_ + i2];
    }
    __syncthreads();  // barrier B
  }
}

// ---------- decode: logits = hs @ Wd^T + bd, single-pass bf16 MFMA ----------
// 128x128 tile, 8 waves (2M x 4N), wave tile 64M x 32N = 4x2 16x16 frags.
__global__ __launch_bounds__(512, 2) void decode_kernel(
    const u16* __restrict__ hs, const u16* __restrict__ wd,
    const float* __restrict__ bd, float* __restrict__ out) {
  const int lane = threadIdx.x & 63;
  const int w = threadIdx.x >> 6;
  const int wm = w >> 2, wn = w & 3;
  const int n0 = blockIdx.x * 128 + wn * 32;
  const int m0 = blockIdx.y * 128 + wm * 64;
  const int kg = (lane >> 4) * 8;
  const int rl = lane & 15;

  short8 bfr[2][2];
#pragma unroll
  for (int nt = 0; nt < 2; ++nt) {
    int v = n0 + nt * 16 + rl;
#pragma unroll
    for (int ks = 0; ks < 2; ++ks)
      bfr[nt][ks] = *(const short8*)(wd + (size_t)v * N_ + ks * 32 + kg);
  }
  short8 a[4][2];
#pragma unroll
  for (int mt = 0; mt < 4; ++mt) {
    int row = m0 + mt * 16 + rl;
#pragma unroll
    for (int ks = 0; ks < 2; ++ks)
      a[mt][ks] = *(const short8*)(hs + (size_t)row * N_ + ks * 32 + kg);
  }
  f32x4 acc[4][2];
#pragma unroll
  for (int nt = 0; nt < 2; ++nt) {
    float bdv = bd[n0 + nt * 16 + rl];
#pragma unroll
    for (int mt = 0; mt < 4; ++mt) acc[mt][nt] = {bdv, bdv, bdv, bdv};
  }
#pragma unroll
  for (int mt = 0; mt < 4; ++mt)
#pragma unroll
    for (int nt = 0; nt < 2; ++nt) {
      acc[mt][nt] =
          __builtin_amdgcn_mfma_f32_16x16x32_bf16(a[mt][0], bfr[nt][0], acc[mt][nt], 0, 0, 0);
      acc[mt][nt] =
          __builtin_amdgcn_mfma_f32_16x16x32_bf16(a[mt][1], bfr[nt][1], acc[mt][nt], 0, 0, 0);
    }
  // C layout: col = lane&15, row = (lane>>4)*4 + i  (verified R1-R6)
#pragma unroll
  for (int mt = 0; mt < 4; ++mt) {
    int rbase = m0 + mt * 16 + (lane >> 4) * 4;
#pragma unroll
    for (int i = 0; i < 4; ++i) {
      float* op = out + (size_t)(rbase + i) * V_ + n0 + rl;
      op[0] = acc[mt][0][i];
      op[16] = acc[mt][1][i];
    }
  }
}

// ---------- launch ----------
extern "C" void kernel_launch(void* const* d_in, const int* in_sizes, int n_in,
                              void* d_out, int out_size, void* d_ws, size_t ws_size,
                              hipStream_t stream) {
  const int* ids = (const int*)d_in[0];
  const float* emb = (const float*)d_in[1];
  const float* W = (const float*)d_in[2];
  const float* Wd = (const float*)d_in[3];
  const float* bd = (const float*)d_in[4];
  float* out = (float*)d_out;
  char* ws = (char*)d_ws;

  // ws layout (bytes):
  // [Wq 262144][wmax 64][rowmax 128000][hs 1 MiB][wd_bf16 4096000]
  u32* Wq = (u32*)(ws);
  u32* wmax = (u32*)(ws + 262144);
  float* rmax = (float*)(ws + 262208);
  u16* hs = (u16*)(ws + 390208);
  u16* wdb = (u16*)(ws + 1438784);

  hipMemsetAsync(wmax, 0, 4, stream);
  hipLaunchKernelGGL(wmax_kernel, dim3(256), dim3(256), 0, stream, W, wmax);
  hipLaunchKernelGGL(quantw_kernel, dim3(256), dim3(256), 0, stream, W, wmax, Wq);
  hipLaunchKernelGGL(rowmax_kernel, dim3(V_ / 4), dim3(256), 0, stream, emb, rmax);
  hipLaunchKernelGGL(wdbf16_kernel, dim3(8000), dim3(256), 0, stream, Wd, wdb);
  hipLaunchKernelGGL(recur_kernel, dim3(NCHUNK_, B_), dim3(512), 0, stream, ids, emb,
                     Wq, wmax, rmax, hs, out + (size_t)B_ * S_ * V_);
  hipLaunchKernelGGL(decode_kernel, dim3(V_ / 128, (B_ * S_) / 128), dim3(512), 0, stream,
                     hs, wdb, bd, out);

  (void)in_sizes; (void)n_in; (void)out_size; (void)ws_size;
}

// Round 8
// 326.988 us; speedup vs baseline: 6.3079x; 1.2015x over previous
//
#include <hip/hip_runtime.h>

// ChemicalLLM: x_{t+1} = norm(relu(x + a*einsum(W,x,x))), then big decode GEMM.
//  R7 result: 393 us. absmax bit-identical across R1-R7 (4.88e-4 = 2^-9
//  * max|Wd| * sum(h)) => binding error is bf16 storage of h; everything
//  else is invisible under that floor, 4.9x margin to threshold.
//  R8 changes:
//  - recur: NCHUNK 32 / CHUNK 32 / WARM 24 -> sequential depth 96->56,
//    256 blocks = all CUs. (Contraction: even gamma=0.5 -> 0.5^24=6e-8.)
//  - decode: nontemporal stores (1.05 GB stream bypasses L2, keeps wd/hs
//    operands resident).
//  - prep: rowmax+wdbf16 fused into one launch.

typedef unsigned int u32;
typedef unsigned short u16;
typedef __attribute__((ext_vector_type(8))) short short8;
typedef __attribute__((ext_vector_type(4))) float f32x4;
typedef __attribute__((ext_vector_type(4))) int i32x4;

#define DECAY_ 0.1f
#define ALPHA_ 0.2f
#define EPS_ 1e-8f
#define B_ 8
#define S_ 1024
#define N_ 64
#define V_ 32000
#define NCHUNK_ 32
#define CHUNK_ 32
#define WARM_ 24

// ---------- bf16 helpers (manual, RNE) ----------
static __device__ __forceinline__ u16 f2bf(float f) {
  u32 u = __float_as_uint(f);
  u32 r = (u + 0x7fffu + ((u >> 16) & 1u)) >> 16;
  return (u16)r;
}

// ---------- int8 dot4 ----------
#if defined(__has_builtin)
#if __has_builtin(__builtin_amdgcn_sdot4)
#define HAVE_SDOT4 1
#endif
#endif
static __device__ __forceinline__ int dot4(int a, int b, int c) {
#ifdef HAVE_SDOT4
  return __builtin_amdgcn_sdot4(a, b, c, false);
#else
  int s = c;
  s += (int)(signed char)(a) * (int)(signed char)(b);
  s += (int)(signed char)(a >> 8) * (int)(signed char)(b >> 8);
  s += (int)(signed char)(a >> 16) * (int)(signed char)(b >> 16);
  s += (int)(a >> 24) * (int)(b >> 24);
  return s;
#endif
}

static __device__ __forceinline__ float wave_max64(float v) {
#pragma unroll
  for (int m = 1; m < 64; m <<= 1) v = fmaxf(v, __shfl_xor(v, m, 64));
  return v;
}

// ---------- prep: |W| max ----------
__global__ void wmax_kernel(const float* __restrict__ W, u32* __restrict__ out) {
  int gid = blockIdx.x * blockDim.x + threadIdx.x;
  int stride = gridDim.x * blockDim.x;
  float m = 0.0f;
  for (int i = gid; i < N_ * N_ * N_; i += stride) m = fmaxf(m, fabsf(W[i]));
  m = wave_max64(m);
  if ((threadIdx.x & 63) == 0) atomicMax(out, __float_as_uint(m));  // f>=0: bits monotone
}

// ---------- prep: quantize+pack W ----------
// canonical dword (j, q, k) packs W[4q+e][j][k], e = byte 0..3.  w=j>>3, r=j&7.
// BOTH halves use layout dst = base + ((jX*4 + q4)*64 + k)*4 + e2,
// jX = w*4 + (r&3); base = 0 (r<4, "L2 half") or 32768 (r>=4, "LDS half").
__global__ void quantw_kernel(const float* __restrict__ W, const u32* __restrict__ wmaxb,
                              u32* __restrict__ Wq) {
  int idx = blockIdx.x * blockDim.x + threadIdx.x;  // 65536 dwords
  float s = 127.0f / fmaxf(__uint_as_float(wmaxb[0]), 1e-30f);
  int j = idx >> 10;
  int q = (idx >> 6) & 15;
  int k = idx & 63;
  u32 pk = 0;
#pragma unroll
  for (int e = 0; e < 4; ++e) {
    float v = W[(((4 * q + e) * N_) + j) * N_ + k];
    int qi = (int)rintf(v * s);
    qi = qi > 127 ? 127 : (qi < -127 ? -127 : qi);
    pk |= ((u32)qi & 0xffu) << (8 * e);
  }
  int w = j >> 3, r = j & 7;
  int jX = w * 4 + (r & 3);
  int base = (r < 4) ? 0 : 32768;
  int q4 = q >> 2, e2 = q & 3;
  Wq[base + (((jX * 4 + q4) * 64 + k) << 2) + e2] = pk;
}

// ---------- prep (fused): Wd -> bf16  +  emb row max ----------
__global__ void prep2_kernel(const float* __restrict__ Wd, u16* __restrict__ wdb,
                             const float* __restrict__ emb, float* __restrict__ rmax) {
  int idx = blockIdx.x * blockDim.x + threadIdx.x;  // 8000*256 = 2048000
  wdb[idx] = f2bf(Wd[idx]);
  int v = blockIdx.x * 4 + (threadIdx.x >> 6);      // 32000 rows
  int lane = threadIdx.x & 63;
  float m = wave_max64(emb[(size_t)v * N_ + lane]);
  if (lane == 0) rmax[v] = fmaxf(m, 0.0f);          // max of relu(row)
}

// ---------- recurrence: blockIdx.y = batch, blockIdx.x = chunk ----------
__global__ __launch_bounds__(512, 2) void recur_kernel(
    const int* __restrict__ ids, const float* __restrict__ emb,
    const u32* __restrict__ Wq, const u32* __restrict__ wmaxb,
    const float* __restrict__ rmax,
    u16* __restrict__ hs, float* __restrict__ outHT) {
  const int b = blockIdx.y;
  const int chunk = blockIdx.x;
  const int lane = threadIdx.x & 63;  // k in dot phase
  const int w = threadIdx.x >> 6;     // wave 0..7, owns j in [8w, 8w+8)

  const int t0 = chunk * CHUNK_;                 // first step this chunk OWNS
  const int ts = (chunk == 0) ? 0 : t0 - WARM_;  // warmup start (h=0 IC exact at t=0)
  const int tend = t0 + CHUNK_;

  __shared__ i32x4 lw[8192];      // 128 KB: LDS half of W, [jB][q4][lane] 16B units
  __shared__ float part[8 * 64];  // raw partials (unscaled)
  __shared__ float xf_lds[N_];    // current x (f32, exact)
  __shared__ u32 xq_lds[16];      // current x quantized u8, 4/dword along i

  const float sW = __uint_as_float(wmaxb[0]) * (1.0f / 127.0f);
  const i32x4* __restrict__ WqA = (const i32x4*)Wq;  // L2 half, x4 layout

  // LDS half: bulk copy region B (already in lw layout)
  {
    const i32x4* src = (const i32x4*)(Wq + 32768);
    for (int ii = threadIdx.x; ii < 8192; ii += 512) lw[ii] = src[ii];
  }

  // wave0-private state
  float xk = 0.0f, smul = 0.0f, pend_emb = 0.0f, pend_bnd = 0.0f;
  int pend_id = 0;

  if (w == 0) {
    int id0 = ids[b * S_ + ts];
    xk = fmaxf(emb[(size_t)id0 * N_ + lane], 0.0f);  // x_ts with h=0 IC
    float bnd = fmaxf(rmax[id0], 1e-20f);            // exact max of x_ts
    smul = bnd * (1.0f / 127.0f) * sW;
    float inv = 127.0f / bnd;
    float u = xk * inv;
    float u0 = __shfl(u, (lane & 15) * 4 + 0, 64);
    float u1 = __shfl(u, (lane & 15) * 4 + 1, 64);
    float u2 = __shfl(u, (lane & 15) * 4 + 2, 64);
    float u3 = __shfl(u, (lane & 15) * 4 + 3, 64);
    xf_lds[lane] = xk;
    if (lane < 16) {
      xq_lds[lane] = (u32)(int)rintf(u0) | ((u32)(int)rintf(u1) << 8) |
                     ((u32)(int)rintf(u2) << 16) | ((u32)(int)rintf(u3) << 24);
    }
    int i1 = ts + 1 < S_ ? ts + 1 : S_ - 1;
    int i2 = ts + 2 < S_ ? ts + 2 : S_ - 1;
    int id1 = ids[b * S_ + i1];
    pend_emb = emb[(size_t)id1 * N_ + lane];
    pend_bnd = rmax[id1];
    pend_id = ids[b * S_ + i2];
  }
  __syncthreads();

  for (int t = ts; t < tend; ++t) {
    // ---- dot phase (all 8 waves): raw partial for this wave's 8 j's ----
    u32 pkv = xq_lds[lane & 15];
    int xr[16];
#pragma unroll
    for (int q = 0; q < 16; ++q) xr[q] = __builtin_amdgcn_readlane((int)pkv, q);
    float pf = 0.0f;
    // LDS half (j = 8w+4+r4)
#pragma unroll
    for (int r4 = 0; r4 < 4; ++r4) {
      int a = 0;
#pragma unroll
      for (int q4 = 0; q4 < 4; ++q4) {
        i32x4 v = lw[(((w << 2) + r4) << 2 | q4) * 64 + lane];
        a = dot4(xr[4 * q4 + 0], v[0], a);
        a = dot4(xr[4 * q4 + 1], v[1], a);
        a = dot4(xr[4 * q4 + 2], v[2], a);
        a = dot4(xr[4 * q4 + 3], v[3], a);
      }
      pf += (float)a * xf_lds[8 * w + 4 + r4];
    }
    // L2 half (j = 8w+r, r<4): streamed dwordx4 each step
#pragma unroll
    for (int r = 0; r < 4; ++r) {
      int a = 0;
#pragma unroll
      for (int q4 = 0; q4 < 4; ++q4) {
        i32x4 v = WqA[(((w << 2) + r) << 2 | q4) * 64 + lane];
        a = dot4(xr[4 * q4 + 0], v[0], a);
        a = dot4(xr[4 * q4 + 1], v[1], a);
        a = dot4(xr[4 * q4 + 2], v[2], a);
        a = dot4(xr[4 * q4 + 3], v[3], a);
      }
      pf += (float)a * xf_lds[8 * w + r];
    }
    part[(w << 6) | lane] = pf;
    __syncthreads();  // barrier A

    // ---- epilogue (wave0 only) ----
    if (w == 0) {
      float iact = 0.0f;
#pragma unroll
      for (int q = 0; q < 8; ++q) iact += part[(q << 6) | lane];
      float xact = fmaxf(fmaf(ALPHA_ * smul, iact, xk), 0.0f);
      float s = xact;
#pragma unroll
      for (int m = 1; m < 64; m <<= 1) s += __shfl_xor(s, m, 64);
      float rS = 1.0f / (s + EPS_);
      float h = xact * rS;

      if (t >= t0) {  // chunk owns this step
        int mrow = b * S_ + t;
        hs[(size_t)mrow * N_ + lane] = f2bf(h);
        if (t == S_ - 1) outHT[b * N_ + lane] = h;
      }

      // next state: x_{t+1} = 0.9 h + relu(emb_{t+1});  max(h) <= 1 always
      float wn = fmaxf(pend_emb, 0.0f);
      float xn = fmaf(1.0f - DECAY_, h, wn);
      float nbnd = (1.0f - DECAY_) + pend_bnd;  // >= true max(xn), >= 0.9
      float inv = 127.0f / nbnd;
      float u = xn * inv;
      float u0 = __shfl(u, (lane & 15) * 4 + 0, 64);
      float u1 = __shfl(u, (lane & 15) * 4 + 1, 64);
      float u2 = __shfl(u, (lane & 15) * 4 + 2, 64);
      float u3 = __shfl(u, (lane & 15) * 4 + 3, 64);
      xf_lds[lane] = xn;
      if (lane < 16) {
        xq_lds[lane] = (u32)(int)rintf(u0) | ((u32)(int)rintf(u1) << 8) |
                       ((u32)(int)rintf(u2) << 16) | ((u32)(int)rintf(u3) << 24);
      }
      smul = nbnd * (1.0f / 127.0f) * sW;
      xk = xn;

      // prefetch for t+2 (clamped; values past tend are unused)
      int i2 = t + 3 < S_ ? t + 3 : S_ - 1;
      pend_emb = emb[(size_t)pend_id * N_ + lane];
      pend_bnd = rmax[pend_id];
      pend_id = ids[b * S_ + i2];
    }
    __syncthreads();  // barrier B
  }
}

// ---------- decode: logits = hs @ Wd^T + bd, single-pass bf16 MFMA ----------
// 128x128 tile, 8 waves (2M x 4N), wave tile 64M x 32N = 4x2 16x16 frags.
__global__ __launch_bounds__(512, 2) void decode_kernel(
    const u16* __restrict__ hs, const u16* __restrict__ wd,
    const float* __restrict__ bd, float* __restrict__ out) {
  const int lane = threadIdx.x & 63;
  const int w = threadIdx.x >> 6;
  const int wm = w >> 2, wn = w & 3;
  const int n0 = blockIdx.x * 128 + wn * 32;
  const int m0 = blockIdx.y * 128 + wm * 64;
  const int kg = (lane >> 4) * 8;
  const int rl = lane & 15;

  short8 bfr[2][2];
#pragma unroll
  for (int nt = 0; nt < 2; ++nt) {
    int v = n0 + nt * 16 + rl;
#pragma unroll
    for (int ks = 0; ks < 2; ++ks)
      bfr[nt][ks] = *(const short8*)(wd + (size_t)v * N_ + ks * 32 + kg);
  }
  short8 a[4][2];
#pragma unroll
  for (int mt = 0; mt < 4; ++mt) {
    int row = m0 + mt * 16 + rl;
#pragma unroll
    for (int ks = 0; ks < 2; ++ks)
      a[mt][ks] = *(const short8*)(hs + (size_t)row * N_ + ks * 32 + kg);
  }
  f32x4 acc[4][2];
#pragma unroll
  for (int nt = 0; nt < 2; ++nt) {
    float bdv = bd[n0 + nt * 16 + rl];
#pragma unroll
    for (int mt = 0; mt < 4; ++mt) acc[mt][nt] = {bdv, bdv, bdv, bdv};
  }
#pragma unroll
  for (int mt = 0; mt < 4; ++mt)
#pragma unroll
    for (int nt = 0; nt < 2; ++nt) {
      acc[mt][nt] =
          __builtin_amdgcn_mfma_f32_16x16x32_bf16(a[mt][0], bfr[nt][0], acc[mt][nt], 0, 0, 0);
      acc[mt][nt] =
          __builtin_amdgcn_mfma_f32_16x16x32_bf16(a[mt][1], bfr[nt][1], acc[mt][nt], 0, 0, 0);
    }
  // C layout: col = lane&15, row = (lane>>4)*4 + i  (verified R1-R7)
#pragma unroll
  for (int mt = 0; mt < 4; ++mt) {
    int rbase = m0 + mt * 16 + (lane >> 4) * 4;
#pragma unroll
    for (int i = 0; i < 4; ++i) {
      float* op = out + (size_t)(rbase + i) * V_ + n0 + rl;
      __builtin_nontemporal_store(acc[mt][0][i], op);
      __builtin_nontemporal_store(acc[mt][1][i], op + 16);
    }
  }
}

// ---------- launch ----------
extern "C" void kernel_launch(void* const* d_in, const int* in_sizes, int n_in,
                              void* d_out, int out_size, void* d_ws, size_t ws_size,
                              hipStream_t stream) {
  const int* ids = (const int*)d_in[0];
  const float* emb = (const float*)d_in[1];
  const float* W = (const float*)d_in[2];
  const float* Wd = (const float*)d_in[3];
  const float* bd = (const float*)d_in[4];
  float* out = (float*)d_out;
  char* ws = (char*)d_ws;

  // ws layout (bytes):
  // [Wq 262144][wmax 64][rowmax 128000][hs 1 MiB][wd_bf16 4096000]
  u32* Wq = (u32*)(ws);
  u32* wmax = (u32*)(ws + 262144);
  float* rmax = (float*)(ws + 262208);
  u16* hs = (u16*)(ws + 390208);
  u16* wdb = (u16*)(ws + 1438784);

  hipMemsetAsync(wmax, 0, 4, stream);
  hipLaunchKernelGGL(wmax_kernel, dim3(256), dim3(256), 0, stream, W, wmax);
  hipLaunchKernelGGL(quantw_kernel, dim3(256), dim3(256), 0, stream, W, wmax, Wq);
  hipLaunchKernelGGL(prep2_kernel, dim3(8000), dim3(256), 0, stream, Wd, wdb, emb, rmax);
  hipLaunchKernelGGL(recur_kernel, dim3(NCHUNK_, B_), dim3(512), 0, stream, ids, emb,
                     Wq, wmax, rmax, hs, out + (size_t)B_ * S_ * V_);
  hipLaunchKernelGGL(decode_kernel, dim3(V_ / 128, (B_ * S_) / 128), dim3(512), 0, stream,
                     hs, wdb, bd, out);

  (void)in_sizes; (void)n_in; (void)out_size; (void)ws_size;
}